// Round 2
// baseline (2196.668 us; speedup 1.0000x reference)
//
#include <hip/hip_runtime.h>

#define NN 25000
#define HH 64
#define EE 400000
#define NH (NN*HH)

// comps layout: c0=I, c1..3 = A01,A02,A12, c4..9 = S00,S01,S02,S11,S12,S22
__device__ __forceinline__ float silu_f(float x){
  return __fdividef(x, 1.0f + __expf(-x));
}

__device__ __forceinline__ void mm3(float* __restrict__ C, const float* __restrict__ A,
                                    const float* __restrict__ B){
  #pragma unroll
  for (int i=0;i<3;i++)
    #pragma unroll
    for (int j=0;j<3;j++)
      C[i*3+j] = A[i*3+0]*B[0*3+j] + A[i*3+1]*B[1*3+j] + A[i*3+2]*B[2*3+j];
}

// M = I*eye + A + S from 10 comps
__device__ __forceinline__ void build3(float* __restrict__ M, const float* __restrict__ c){
  M[0] =  c[0]+c[4]; M[1] =  c[1]+c[5]; M[2] =  c[2]+c[6];
  M[3] = -c[1]+c[5]; M[4] =  c[0]+c[7]; M[5] =  c[3]+c[8];
  M[6] = -c[2]+c[6]; M[7] = -c[3]+c[8]; M[8] =  c[0]+c[9];
}

__device__ __forceinline__ void decomp3(const float* __restrict__ M, float* __restrict__ c){
  float I = (M[0]+M[4]+M[8]) * (1.0f/3.0f);
  c[0]=I;
  c[1]=0.5f*(M[1]-M[3]); c[2]=0.5f*(M[2]-M[6]); c[3]=0.5f*(M[5]-M[7]);
  c[4]=M[0]-I; c[5]=0.5f*(M[1]+M[3]); c[6]=0.5f*(M[2]+M[6]);
  c[7]=M[4]-I; c[8]=0.5f*(M[5]+M[7]); c[9]=M[8]-I;
}

// normalize X by (|X|^2+1) and write 10 decomposed planes
__global__ __launch_bounds__(256) void k_prep(const float* __restrict__ X, float* __restrict__ XD){
  int idx = blockIdx.x*256 + threadIdx.x;
  if (idx >= NH) return;
  const float* t = X + (size_t)idx*9;
  float m[9];
  float n2 = 0.f;
  #pragma unroll
  for (int i=0;i<9;i++){ m[i] = t[i]; n2 += m[i]*m[i]; }
  float inv = __fdividef(1.0f, n2 + 1.0f);
  #pragma unroll
  for (int i=0;i<9;i++) m[i] *= inv;
  float c[10]; decomp3(m, c);
  #pragma unroll
  for (int i=0;i<10;i++) XD[i*NH + idx] = c[i];
}

// Generic register-tiled fp32 GEMM: Out[M,NOUT] = act(In[M,K] @ W[NOUT,K]^T + b)
// mode 0: silu(x+b); mode 1: silu(x+b)*cutoff(ew); mode 2: plain x
// macro-tile 128 rows x NT cols, thread tile 8 x TO, LDS xor-swizzled.
template<int K, int KS, int NT, int TO, int NOUT>
__global__ __launch_bounds__(256) void k_gemm(const float* __restrict__ In,
                       const float* __restrict__ W,
                       const float* __restrict__ bias, float* __restrict__ Out,
                       int M, int mode, const float* __restrict__ ew){
  constexpr int KSP = KS + 4;
  constexpr int F4R = KS/4;
  __shared__ __align__(16) float sA[128*KSP];
  __shared__ __align__(16) float sW[NT*KSP];
  const int tid = threadIdx.x;
  const int te = tid >> 4;   // 0..15 row-group (8 rows each)
  const int to = tid & 15;   // 0..15 col-group (TO cols each)
  const int e0 = blockIdx.x * 128;
  const int ob = blockIdx.y * NT;
  float acc[8][TO];
  #pragma unroll
  for (int s=0;s<8;s++)
    #pragma unroll
    for (int r=0;r<TO;r++) acc[s][r]=0.f;

  for (int kb = 0; kb < K; kb += KS){
    if (kb) __syncthreads();
    #pragma unroll
    for (int g = 0; g < 128*F4R/256; g++){
      int gi = tid + g*256;
      int row = gi / F4R, c4 = gi % F4R;
      float4 v = make_float4(0.f,0.f,0.f,0.f);
      if (e0 + row < M) v = *(const float4*)&In[(size_t)(e0+row)*K + kb + c4*4];
      int c4p = c4 ^ ((row>>3)&3);   // xor-swizzle: kills row-group bank conflicts
      *(float4*)&sA[row*KSP + c4p*4] = v;
    }
    #pragma unroll
    for (int g = 0; g < NT*F4R/256; g++){
      int gi = tid + g*256;
      int row = gi / F4R, c4 = gi % F4R;
      float4 v = *(const float4*)&W[(size_t)(ob+row)*K + kb + c4*4];
      int c4p = c4 ^ ((row>>3)&3);
      *(float4*)&sW[row*KSP + c4p*4] = v;
    }
    __syncthreads();
    #pragma unroll 4
    for (int k4 = 0; k4 < F4R; k4++){
      float4 aa[8], ww[TO];
      #pragma unroll
      for (int s=0;s<8;s++){
        int row = te*8+s;
        aa[s] = *(const float4*)&sA[row*KSP + (k4 ^ ((row>>3)&3))*4];
      }
      #pragma unroll
      for (int r=0;r<TO;r++){
        int row = to*TO+r;
        ww[r] = *(const float4*)&sW[row*KSP + (k4 ^ ((row>>3)&3))*4];
      }
      #pragma unroll
      for (int s=0;s<8;s++)
        #pragma unroll
        for (int r=0;r<TO;r++){
          acc[s][r] += aa[s].x*ww[r].x;
          acc[s][r] += aa[s].y*ww[r].y;
          acc[s][r] += aa[s].z*ww[r].z;
          acc[s][r] += aa[s].w*ww[r].w;
        }
    }
  }
  #pragma unroll
  for (int s=0;s<8;s++){
    int eg = e0 + te*8 + s;
    if (eg >= M) continue;
    float cmul = 1.0f;
    if (mode == 1){
      float w = ew[eg];
      cmul = 0.5f*(__cosf(w*0.6283185307179586f)+1.0f);
      cmul = (w < 5.0f) ? cmul : 0.0f;
    }
    #pragma unroll
    for (int r=0;r<TO;r++){
      int o = ob + to*TO + r;
      float v = acc[s][r];
      if (mode != 2){
        v += bias[o];
        v = silu_f(v);
        v *= cmul;
      }
      Out[(size_t)eg*NOUT + o] = v;
    }
  }
}

// wave-per-edge scatter: Y[dst] += f0*I[src], f1*A[src], f2*S[src]
// processes chunk-local edges [0,ce) mapping to global edges e0+el
__global__ __launch_bounds__(256) void k_agg(const int* __restrict__ ei, const float* __restrict__ F,
                      const float* __restrict__ XD, float* __restrict__ Y, int e0, int ce){
  int el = blockIdx.x*4 + (threadIdx.x>>6);
  int lane = threadIdx.x & 63;
  if (el >= ce) return;
  int e = e0 + el;
  int dst = ei[e]*64 + lane;
  int src = ei[EE+e]*64 + lane;
  const float* fp = F + (size_t)el*192 + lane*3;
  float f0 = fp[0], f1 = fp[1], f2 = fp[2];
  atomicAdd(&Y[0*NH+dst], f0*XD[0*NH+src]);
  atomicAdd(&Y[1*NH+dst], f1*XD[1*NH+src]);
  atomicAdd(&Y[2*NH+dst], f1*XD[2*NH+src]);
  atomicAdd(&Y[3*NH+dst], f1*XD[3*NH+src]);
  atomicAdd(&Y[4*NH+dst], f2*XD[4*NH+src]);
  atomicAdd(&Y[5*NH+dst], f2*XD[5*NH+src]);
  atomicAdd(&Y[6*NH+dst], f2*XD[6*NH+src]);
  atomicAdd(&Y[7*NH+dst], f2*XD[7*NH+src]);
  atomicAdd(&Y[8*NH+dst], f2*XD[8*NH+src]);
  atomicAdd(&Y[9*NH+dst], f2*XD[9*NH+src]);
}

// per (n,h): Xnew = Y@Xin + Xin@Y, normalize, decompose -> XM (in-place over XI)
__global__ __launch_bounds__(256) void k_combine(const float* __restrict__ XI, const float* __restrict__ Y,
                          float* __restrict__ XM){
  int idx = blockIdx.x*256 + threadIdx.x;
  if (idx >= NH) return;
  float xi[10], yc[10];
  #pragma unroll
  for (int c=0;c<10;c++){ xi[c]=XI[c*NH+idx]; yc[c]=Y[c*NH+idx]; }
  float Xin[9], Ym[9], Am[9], Bm[9];
  build3(Xin, xi); build3(Ym, yc);
  mm3(Am, Ym, Xin);
  mm3(Bm, Xin, Ym);
  float Xn[9]; float n2 = 0.f;
  #pragma unroll
  for (int i=0;i<9;i++){ Xn[i] = Am[i]+Bm[i]; n2 += Xn[i]*Xn[i]; }
  float inv = __fdividef(1.0f, n2 + 1.0f);
  #pragma unroll
  for (int i=0;i<9;i++) Xn[i] *= inv;
  float c[10]; decomp3(Xn, c);
  #pragma unroll
  for (int i=0;i<10;i++) XM[i*NH+idx] = c[i];
}

// out = Xn + (dX + dX@dX) * (1 + 0.1 q)
__global__ __launch_bounds__(256) void k_final(const float* __restrict__ XD, const float* __restrict__ XO,
                        const float* __restrict__ q, float* __restrict__ out){
  int idx = blockIdx.x*256 + threadIdx.x;
  if (idx >= NH) return;
  float xd[10], xo[10];
  #pragma unroll
  for (int c=0;c<10;c++){ xd[c]=XD[c*NH+idx]; xo[c]=XO[c*NH+idx]; }
  float Xn[9], dX[9], D2[9];
  build3(Xn, xd); build3(dX, xo);
  mm3(D2, dX, dX);
  float cf = 1.0f + 0.1f*q[idx>>6];
  float* o = out + (size_t)idx*9;
  #pragma unroll
  for (int i=0;i<9;i++) o[i] = Xn[i] + (dX[i]+D2[i])*cf;
}

extern "C" void kernel_launch(void* const* d_in, const int* in_sizes, int n_in,
                              void* d_out, int out_size, void* d_ws, size_t ws_size,
                              hipStream_t stream) {
  const float* X   = (const float*)d_in[0];
  const int*   ei  = (const int*)  d_in[1];
  const float* ew  = (const float*)d_in[2];
  const float* ea  = (const float*)d_in[3];
  const float* q   = (const float*)d_in[4];
  const float* W1  = (const float*)d_in[5];
  const float* b1  = (const float*)d_in[6];
  const float* W2  = (const float*)d_in[7];
  const float* b2  = (const float*)d_in[8];
  const float* W3  = (const float*)d_in[9];
  const float* b3  = (const float*)d_in[10];
  const float* WIi = (const float*)d_in[11];
  const float* WAi = (const float*)d_in[12];
  const float* WSi = (const float*)d_in[13];
  const float* WIo = (const float*)d_in[14];
  const float* WAo = (const float*)d_in[15];
  const float* WSo = (const float*)d_in[16];
  float* out = (float*)d_out;

  float* ws = (float*)d_ws;
  float* XD = ws;                        // 10*NH floats (64 MB)
  float* Y  = XD + (size_t)10*NH;        // 10*NH (later reused as XO)
  float* XI = Y  + (size_t)10*NH;        // 10*NH (later reused as XM)
  float* H1 = XI + (size_t)10*NH;        // chunkE*64
  // edge scratch: 384 floats per edge (H1 64 + H2 128 + F 192), chunked to fit ws_size
  size_t node_f  = (size_t)30*NH;
  size_t avail_f = (ws_size/4 > node_f) ? (ws_size/4 - node_f) : 0;
  long long cmax = (long long)(avail_f / 384);
  int chunkE = (int)((cmax/128)*128);
  if (chunkE < 128) chunkE = 128;
  if (chunkE > EE)  chunkE = EE;

  hipMemsetAsync(Y, 0, (size_t)10*NH*sizeof(float), stream);
  k_prep<<<NH/256, 256, 0, stream>>>(X, XD);

  // edge MLP (32 -> 64 -> 128 -> 192, silu; layer3 * cosine cutoff) + scatter, chunked
  for (int e0 = 0; e0 < EE; e0 += chunkE){
    int ce = EE - e0 < chunkE ? EE - e0 : chunkE;
    int gb = (ce + 127)/128;
    float* H2 = H1 + (size_t)chunkE*64;
    float* F  = H2 + (size_t)chunkE*128;
    k_gemm<32,32,64,4,64 ><<<dim3(gb,1), 256, 0, stream>>>(ea + (size_t)e0*32, W1, b1, H1, ce, 0, nullptr);
    k_gemm<64,64,64,4,128><<<dim3(gb,2), 256, 0, stream>>>(H1, W2, b2, H2, ce, 0, nullptr);
    k_gemm<128,64,96,6,192><<<dim3(gb,2),256, 0, stream>>>(H2, W3, b3, F,  ce, 1, ew + e0);
    k_agg<<<(ce+3)/4, 256, 0, stream>>>(ei, F, XD, Y, e0, ce);
  }

  // Xin = tensor_linear(Xn): three plane GEMMs (I / A / S share their W)
  k_gemm<64,64,64,4,64><<<dim3((NN   +127)/128,1),256,0,stream>>>(XD,                 WIi, nullptr, XI,                 NN,   2, nullptr);
  k_gemm<64,64,64,4,64><<<dim3((3*NN +127)/128,1),256,0,stream>>>(XD + (size_t)NH,    WAi, nullptr, XI + (size_t)NH,    3*NN, 2, nullptr);
  k_gemm<64,64,64,4,64><<<dim3((6*NN +127)/128,1),256,0,stream>>>(XD + (size_t)4*NH,  WSi, nullptr, XI + (size_t)4*NH,  6*NN, 2, nullptr);

  k_combine<<<NH/256, 256, 0, stream>>>(XI, Y, XI);   // XI now holds XM planes

  float* XO = Y;  // Y consumed; reuse as output-mix buffer
  k_gemm<64,64,64,4,64><<<dim3((NN   +127)/128,1),256,0,stream>>>(XI,                 WIo, nullptr, XO,                 NN,   2, nullptr);
  k_gemm<64,64,64,4,64><<<dim3((3*NN +127)/128,1),256,0,stream>>>(XI + (size_t)NH,    WAo, nullptr, XO + (size_t)NH,    3*NN, 2, nullptr);
  k_gemm<64,64,64,4,64><<<dim3((6*NN +127)/128,1),256,0,stream>>>(XI + (size_t)4*NH,  WSo, nullptr, XO + (size_t)4*NH,  6*NN, 2, nullptr);

  k_final<<<NH/256, 256, 0, stream>>>(XD, XO, q, out);
}

// Round 4
// 1472.273 us; speedup vs baseline: 1.4920x; 1.4920x over previous
//
#include <hip/hip_runtime.h>

#define NN 25000
#define HH 64
#define EE 400000
#define NH (NN*HH)

typedef __attribute__((ext_vector_type(8))) short bf16x8;
typedef __attribute__((ext_vector_type(4))) float f32x4;

__device__ __forceinline__ float silu_f(float x){
  return __fdividef(x, 1.0f + __expf(-x));
}
__device__ __forceinline__ short f2bf(float x){
  unsigned u = __float_as_uint(x);
  unsigned r = (u + 0x7FFFu + ((u>>16)&1u)) >> 16;
  return (short)r;
}
__device__ __forceinline__ float bf2f(short h){
  return __uint_as_float(((unsigned)(unsigned short)h)<<16);
}
__device__ __forceinline__ void st_hilo(char* bh, char* bl, int elem, float x){
  short hi = f2bf(x);
  short lo = f2bf(x - bf2f(hi));
  ((short*)bh)[elem] = hi;
  ((short*)bl)[elem] = lo;
}
// 4-term split product: (ah+al)(bh+bl) — error ~2^-18 relative
__device__ __forceinline__ f32x4 mfma4(bf16x8 ah, bf16x8 al, bf16x8 bh, bf16x8 bl, f32x4 acc){
  acc = __builtin_amdgcn_mfma_f32_16x16x32_bf16(ah, bh, acc, 0, 0, 0);
  acc = __builtin_amdgcn_mfma_f32_16x16x32_bf16(ah, bl, acc, 0, 0, 0);
  acc = __builtin_amdgcn_mfma_f32_16x16x32_bf16(al, bh, acc, 0, 0, 0);
  acc = __builtin_amdgcn_mfma_f32_16x16x32_bf16(al, bl, acc, 0, 0, 0);
  return acc;
}

__device__ __forceinline__ void mm3(float* __restrict__ C, const float* __restrict__ A,
                                    const float* __restrict__ B){
  #pragma unroll
  for (int i=0;i<3;i++)
    #pragma unroll
    for (int j=0;j<3;j++)
      C[i*3+j] = A[i*3+0]*B[0*3+j] + A[i*3+1]*B[1*3+j] + A[i*3+2]*B[2*3+j];
}
__device__ __forceinline__ void build3(float* __restrict__ M, const float* __restrict__ c){
  M[0] =  c[0]+c[4]; M[1] =  c[1]+c[5]; M[2] =  c[2]+c[6];
  M[3] = -c[1]+c[5]; M[4] =  c[0]+c[7]; M[5] =  c[3]+c[8];
  M[6] = -c[2]+c[6]; M[7] = -c[3]+c[8]; M[8] =  c[0]+c[9];
}
__device__ __forceinline__ void decomp3(const float* __restrict__ M, float* __restrict__ c){
  float I = (M[0]+M[4]+M[8]) * (1.0f/3.0f);
  c[0]=I;
  c[1]=0.5f*(M[1]-M[3]); c[2]=0.5f*(M[2]-M[6]); c[3]=0.5f*(M[5]-M[7]);
  c[4]=M[0]-I; c[5]=0.5f*(M[1]+M[3]); c[6]=0.5f*(M[2]+M[6]);
  c[7]=M[4]-I; c[8]=0.5f*(M[5]+M[7]); c[9]=M[8]-I;
}

__global__ __launch_bounds__(256) void k_prep(const float* __restrict__ X, float* __restrict__ XD){
  int idx = blockIdx.x*256 + threadIdx.x;
  if (idx >= NH) return;
  const float* t = X + (size_t)idx*9;
  float m[9];
  float n2 = 0.f;
  #pragma unroll
  for (int i=0;i<9;i++){ m[i] = t[i]; n2 += m[i]*m[i]; }
  float inv = __fdividef(1.0f, n2 + 1.0f);
  #pragma unroll
  for (int i=0;i<9;i++) m[i] *= inv;
  float c[10]; decomp3(m, c);
  #pragma unroll
  for (int i=0;i<10;i++) XD[i*NH + idx] = c[i];
}

// ---------------- fused edge pipeline: MLP(32->64->128->192, silu, cutoff) + scatter ---------
// block = 256 thr (4 waves), 64 edges. All activations stay in LDS as split-bf16.
#define O_H1H 0
#define O_H1L 9216
#define O_H2H 18432
#define O_H2L 35840
#define O_EAH 18432
#define O_EAL 23552
#define O_W   53248
#define O_F   0
#define O_CUT 79360
#define SMEM_BYTES 79616

__global__ __launch_bounds__(256) void k_edge_fused(
    const float* __restrict__ ea, const float* __restrict__ ew,
    const int* __restrict__ ei,
    const float* __restrict__ W1, const float* __restrict__ b1,
    const float* __restrict__ W2, const float* __restrict__ b2,
    const float* __restrict__ W3, const float* __restrict__ b3,
    const float* __restrict__ XD, float* __restrict__ Y)
{
  __shared__ char smem[SMEM_BYTES] __attribute__((aligned(16)));
  const int tid  = threadIdx.x;
  const int w    = tid >> 6;
  const int l    = tid & 63;
  const int quad = l >> 4;
  const int nin  = l & 15;
  const int e0   = blockIdx.x * 64;

  // ---- P0: stage edge_attr (hi/lo) + W1 (hi/lo) + cutoffs ----
  #pragma unroll
  for (int g=0; g<2; g++){                       // 512 float4 over EA
    int gi = tid + g*256;
    int row = gi >> 3, c4 = gi & 7;
    float4 v = *(const float4*)&ea[(size_t)(e0+row)*32 + c4*4];
    int be = row*40 + c4*4;
    st_hilo(smem+O_EAH, smem+O_EAL, be+0, v.x);
    st_hilo(smem+O_EAH, smem+O_EAL, be+1, v.y);
    st_hilo(smem+O_EAH, smem+O_EAL, be+2, v.z);
    st_hilo(smem+O_EAH, smem+O_EAL, be+3, v.w);
  }
  #pragma unroll
  for (int g=0; g<2; g++){                       // 512 float4 over W1 [64][32]
    int gi = tid + g*256;
    int row = gi >> 3, c4 = gi & 7;
    float4 v = *(const float4*)&W1[(size_t)row*32 + c4*4];
    int be = row*40 + c4*4;
    st_hilo(smem+O_W, smem+O_W+5120, be+0, v.x);
    st_hilo(smem+O_W, smem+O_W+5120, be+1, v.y);
    st_hilo(smem+O_W, smem+O_W+5120, be+2, v.z);
    st_hilo(smem+O_W, smem+O_W+5120, be+3, v.w);
  }
  if (tid < 64){
    float wv = ew[e0+tid];
    float c = 0.5f*(__cosf(wv*0.6283185307179586f)+1.0f);
    ((float*)(smem+O_CUT))[tid] = (wv < 5.0f) ? c : 0.0f;
  }
  __syncthreads();

  // ---- P1: H1 = silu(EA @ W1^T + b1), M=64 N=64 K=32 ----
  {
    bf16x8 ah = *(const bf16x8*)(smem + O_EAH + (w*16+nin)*80 + quad*16);
    bf16x8 al = *(const bf16x8*)(smem + O_EAL + (w*16+nin)*80 + quad*16);
    f32x4 acc[4];
    #pragma unroll
    for (int nt=0; nt<4; nt++){
      f32x4 z = {0.f,0.f,0.f,0.f};
      bf16x8 bh = *(const bf16x8*)(smem + O_W        + (nt*16+nin)*80 + quad*16);
      bf16x8 bl = *(const bf16x8*)(smem + O_W + 5120 + (nt*16+nin)*80 + quad*16);
      acc[nt] = mfma4(ah, al, bh, bl, z);
    }
    #pragma unroll
    for (int nt=0; nt<4; nt++){
      float bb = b1[nt*16+nin];
      #pragma unroll
      for (int r=0; r<4; r++){
        float v = silu_f(acc[nt][r] + bb);
        int row = w*16 + quad*4 + r, col = nt*16 + nin;
        short hi = f2bf(v); short lo = f2bf(v - bf2f(hi));
        ((short*)(smem+O_H1H))[row*72 + col] = hi;
        ((short*)(smem+O_H1L))[row*72 + col] = lo;
      }
    }
  }

  // ---- P2: H2 = silu(H1 @ W2^T + b2), M=64 N=128 K=64, W2 staged in 2 halves ----
  {
    f32x4 acc[8];
    #pragma unroll
    for (int i=0;i<8;i++){ f32x4 z = {0.f,0.f,0.f,0.f}; acc[i]=z; }
    for (int half=0; half<2; half++){
      __syncthreads();            // H1 visible (half0) / prior W reads done (half1)
      #pragma unroll
      for (int g=0; g<4; g++){    // 1024 float4 over W2 half [64][64]
        int gi = tid + g*256;
        int row = gi >> 4, c4 = gi & 15;
        float4 v = *(const float4*)&W2[(size_t)(half*64+row)*64 + c4*4];
        int be = row*72 + c4*4;
        st_hilo(smem+O_W, smem+O_W+9216, be+0, v.x);
        st_hilo(smem+O_W, smem+O_W+9216, be+1, v.y);
        st_hilo(smem+O_W, smem+O_W+9216, be+2, v.z);
        st_hilo(smem+O_W, smem+O_W+9216, be+3, v.w);
      }
      __syncthreads();
      #pragma unroll
      for (int kt=0; kt<2; kt++){
        bf16x8 ah = *(const bf16x8*)(smem + O_H1H + (w*16+nin)*144 + kt*64 + quad*16);
        bf16x8 al = *(const bf16x8*)(smem + O_H1L + (w*16+nin)*144 + kt*64 + quad*16);
        #pragma unroll
        for (int nt=0; nt<4; nt++){
          bf16x8 bh = *(const bf16x8*)(smem + O_W        + (nt*16+nin)*144 + kt*64 + quad*16);
          bf16x8 bl = *(const bf16x8*)(smem + O_W + 9216 + (nt*16+nin)*144 + kt*64 + quad*16);
          acc[half*4+nt] = mfma4(ah, al, bh, bl, acc[half*4+nt]);
        }
      }
    }
    // write H2 (own rows; region disjoint from W, EA long dead)
    #pragma unroll
    for (int nt=0; nt<8; nt++){
      float bb = b2[nt*16+nin];
      #pragma unroll
      for (int r=0; r<4; r++){
        float v = silu_f(acc[nt][r] + bb);
        int row = w*16 + quad*4 + r, col = nt*16 + nin;
        short hi = f2bf(v); short lo = f2bf(v - bf2f(hi));
        ((short*)(smem+O_H2H))[row*136 + col] = hi;
        ((short*)(smem+O_H2L))[row*136 + col] = lo;
      }
    }
  }

  // ---- P3: F = silu(H2 @ W3^T + b3) * cutoff, M=64 N=192 K=128, W3 in 4 blocks of 48 ----
  f32x4 acc3[12];
  #pragma unroll
  for (int i=0;i<12;i++){ f32x4 z = {0.f,0.f,0.f,0.f}; acc3[i]=z; }
  for (int nb=0; nb<4; nb++){
    __syncthreads();              // H2 visible (nb0) / prior W reads done
    #pragma unroll
    for (int g=0; g<6; g++){      // 1536 float4 over W3 block [48][128]
      int gi = tid + g*256;
      int row = gi >> 5, c4 = gi & 31;
      float4 v = *(const float4*)&W3[(size_t)(nb*48+row)*128 + c4*4];
      int be = row*136 + c4*4;
      st_hilo(smem+O_W, smem+O_W+13056, be+0, v.x);
      st_hilo(smem+O_W, smem+O_W+13056, be+1, v.y);
      st_hilo(smem+O_W, smem+O_W+13056, be+2, v.z);
      st_hilo(smem+O_W, smem+O_W+13056, be+3, v.w);
    }
    __syncthreads();
    #pragma unroll
    for (int kt=0; kt<4; kt++){
      bf16x8 ah = *(const bf16x8*)(smem + O_H2H + (w*16+nin)*272 + kt*64 + quad*16);
      bf16x8 al = *(const bf16x8*)(smem + O_H2L + (w*16+nin)*272 + kt*64 + quad*16);
      #pragma unroll
      for (int nt=0; nt<3; nt++){
        bf16x8 bh = *(const bf16x8*)(smem + O_W         + (nt*16+nin)*272 + kt*64 + quad*16);
        bf16x8 bl = *(const bf16x8*)(smem + O_W + 13056 + (nt*16+nin)*272 + kt*64 + quad*16);
        acc3[nb*3+nt] = mfma4(ah, al, bh, bl, acc3[nb*3+nt]);
      }
    }
  }
  __syncthreads();                // all H2 reads done; F aliases H1/H2
  #pragma unroll
  for (int nt=0; nt<12; nt++){
    float bb = b3[nt*16+nin];
    #pragma unroll
    for (int r=0; r<4; r++){
      int row = w*16 + quad*4 + r, col = nt*16 + nin;
      float v = silu_f(acc3[nt][r] + bb) * ((float*)(smem+O_CUT))[row];
      ((float*)(smem+O_F))[row*196 + col] = v;
    }
  }
  __syncthreads();

  // ---- P5: scatter — each wave handles its own 16 edges, lane = channel h ----
  for (int t=0; t<16; t++){
    int el = w*16 + t;
    int e  = e0 + el;
    int dst = ei[e]*64 + l;
    int src = ei[EE+e]*64 + l;
    const float* fb = (const float*)(smem + O_F + el*784 + l*12);
    float f0 = fb[0], f1 = fb[1], f2 = fb[2];
    atomicAdd(&Y[0*NH+dst], f0*XD[0*NH+src]);
    atomicAdd(&Y[1*NH+dst], f1*XD[1*NH+src]);
    atomicAdd(&Y[2*NH+dst], f1*XD[2*NH+src]);
    atomicAdd(&Y[3*NH+dst], f1*XD[3*NH+src]);
    atomicAdd(&Y[4*NH+dst], f2*XD[4*NH+src]);
    atomicAdd(&Y[5*NH+dst], f2*XD[5*NH+src]);
    atomicAdd(&Y[6*NH+dst], f2*XD[6*NH+src]);
    atomicAdd(&Y[7*NH+dst], f2*XD[7*NH+src]);
    atomicAdd(&Y[8*NH+dst], f2*XD[8*NH+src]);
    atomicAdd(&Y[9*NH+dst], f2*XD[9*NH+src]);
  }
}

// ---------------- node-side fp32 GEMM (plane channel mixing) -------------
template<int K, int KS, int NT, int TO, int NOUT>
__global__ __launch_bounds__(256) void k_gemm(const float* __restrict__ In,
                       const float* __restrict__ W,
                       const float* __restrict__ bias, float* __restrict__ Out,
                       int M, int mode, const float* __restrict__ ew){
  constexpr int KSP = KS + 4;
  constexpr int F4R = KS/4;
  __shared__ __align__(16) float sA[128*KSP];
  __shared__ __align__(16) float sW[NT*KSP];
  const int tid = threadIdx.x;
  const int te = tid >> 4;
  const int to = tid & 15;
  const int e0 = blockIdx.x * 128;
  const int ob = blockIdx.y * NT;
  float acc[8][TO];
  #pragma unroll
  for (int s=0;s<8;s++)
    #pragma unroll
    for (int r=0;r<TO;r++) acc[s][r]=0.f;

  for (int kb = 0; kb < K; kb += KS){
    if (kb) __syncthreads();
    #pragma unroll
    for (int g = 0; g < 128*F4R/256; g++){
      int gi = tid + g*256;
      int row = gi / F4R, c4 = gi % F4R;
      float4 v = make_float4(0.f,0.f,0.f,0.f);
      if (e0 + row < M) v = *(const float4*)&In[(size_t)(e0+row)*K + kb + c4*4];
      int c4p = c4 ^ ((row>>3)&3);
      *(float4*)&sA[row*KSP + c4p*4] = v;
    }
    #pragma unroll
    for (int g = 0; g < NT*F4R/256; g++){
      int gi = tid + g*256;
      int row = gi / F4R, c4 = gi % F4R;
      float4 v = *(const float4*)&W[(size_t)(ob+row)*K + kb + c4*4];
      int c4p = c4 ^ ((row>>3)&3);
      *(float4*)&sW[row*KSP + c4p*4] = v;
    }
    __syncthreads();
    #pragma unroll 4
    for (int k4 = 0; k4 < F4R; k4++){
      float4 aa[8], ww[TO];
      #pragma unroll
      for (int s=0;s<8;s++){
        int row = te*8+s;
        aa[s] = *(const float4*)&sA[row*KSP + (k4 ^ ((row>>3)&3))*4];
      }
      #pragma unroll
      for (int r=0;r<TO;r++){
        int row = to*TO+r;
        ww[r] = *(const float4*)&sW[row*KSP + (k4 ^ ((row>>3)&3))*4];
      }
      #pragma unroll
      for (int s=0;s<8;s++)
        #pragma unroll
        for (int r=0;r<TO;r++){
          acc[s][r] += aa[s].x*ww[r].x;
          acc[s][r] += aa[s].y*ww[r].y;
          acc[s][r] += aa[s].z*ww[r].z;
          acc[s][r] += aa[s].w*ww[r].w;
        }
    }
  }
  #pragma unroll
  for (int s=0;s<8;s++){
    int eg = e0 + te*8 + s;
    if (eg >= M) continue;
    #pragma unroll
    for (int r=0;r<TO;r++){
      int o = ob + to*TO + r;
      Out[(size_t)eg*NOUT + o] = acc[s][r];
    }
  }
}

__global__ __launch_bounds__(256) void k_combine(const float* __restrict__ XI, const float* __restrict__ Y,
                          float* __restrict__ XM){
  int idx = blockIdx.x*256 + threadIdx.x;
  if (idx >= NH) return;
  float xi[10], yc[10];
  #pragma unroll
  for (int c=0;c<10;c++){ xi[c]=XI[c*NH+idx]; yc[c]=Y[c*NH+idx]; }
  float Xin[9], Ym[9], Am[9], Bm[9];
  build3(Xin, xi); build3(Ym, yc);
  mm3(Am, Ym, Xin);
  mm3(Bm, Xin, Ym);
  float Xn[9]; float n2 = 0.f;
  #pragma unroll
  for (int i=0;i<9;i++){ Xn[i] = Am[i]+Bm[i]; n2 += Xn[i]*Xn[i]; }
  float inv = __fdividef(1.0f, n2 + 1.0f);
  #pragma unroll
  for (int i=0;i<9;i++) Xn[i] *= inv;
  float c[10]; decomp3(Xn, c);
  #pragma unroll
  for (int i=0;i<10;i++) XM[i*NH+idx] = c[i];
}

__global__ __launch_bounds__(256) void k_final(const float* __restrict__ XD, const float* __restrict__ XO,
                        const float* __restrict__ q, float* __restrict__ out){
  int idx = blockIdx.x*256 + threadIdx.x;
  if (idx >= NH) return;
  float xd[10], xo[10];
  #pragma unroll
  for (int c=0;c<10;c++){ xd[c]=XD[c*NH+idx]; xo[c]=XO[c*NH+idx]; }
  float Xn[9], dX[9], D2[9];
  build3(Xn, xd); build3(dX, xo);
  mm3(D2, dX, dX);
  float cf = 1.0f + 0.1f*q[idx>>6];
  float* o = out + (size_t)idx*9;
  #pragma unroll
  for (int i=0;i<9;i++) o[i] = Xn[i] + (dX[i]+D2[i])*cf;
}

extern "C" void kernel_launch(void* const* d_in, const int* in_sizes, int n_in,
                              void* d_out, int out_size, void* d_ws, size_t ws_size,
                              hipStream_t stream) {
  const float* X   = (const float*)d_in[0];
  const int*   ei  = (const int*)  d_in[1];
  const float* ew  = (const float*)d_in[2];
  const float* ea  = (const float*)d_in[3];
  const float* q   = (const float*)d_in[4];
  const float* W1  = (const float*)d_in[5];
  const float* b1  = (const float*)d_in[6];
  const float* W2  = (const float*)d_in[7];
  const float* b2  = (const float*)d_in[8];
  const float* W3  = (const float*)d_in[9];
  const float* b3  = (const float*)d_in[10];
  const float* WIi = (const float*)d_in[11];
  const float* WAi = (const float*)d_in[12];
  const float* WSi = (const float*)d_in[13];
  const float* WIo = (const float*)d_in[14];
  const float* WAo = (const float*)d_in[15];
  const float* WSo = (const float*)d_in[16];
  float* out = (float*)d_out;

  float* ws = (float*)d_ws;
  float* XD = ws;                        // 10*NH floats
  float* Y  = XD + (size_t)10*NH;        // 10*NH (later reused as XO)
  float* XI = Y  + (size_t)10*NH;        // 10*NH (later reused as XM)

  hipMemsetAsync(Y, 0, (size_t)10*NH*sizeof(float), stream);
  k_prep<<<NH/256, 256, 0, stream>>>(X, XD);

  // fused edge pipeline: MLP + cutoff + gather/scatter, zero global edge scratch
  k_edge_fused<<<EE/64, 256, 0, stream>>>(ea, ew, ei, W1, b1, W2, b2, W3, b3, XD, Y);

  // Xin = tensor_linear(Xn): three plane GEMMs (I / A / S share their W)
  k_gemm<64,64,64,4,64><<<dim3((NN   +127)/128,1),256,0,stream>>>(XD,                 WIi, nullptr, XI,                 NN,   2, nullptr);
  k_gemm<64,64,64,4,64><<<dim3((3*NN +127)/128,1),256,0,stream>>>(XD + (size_t)NH,    WAi, nullptr, XI + (size_t)NH,    3*NN, 2, nullptr);
  k_gemm<64,64,64,4,64><<<dim3((6*NN +127)/128,1),256,0,stream>>>(XD + (size_t)4*NH,  WSi, nullptr, XI + (size_t)4*NH,  6*NN, 2, nullptr);

  k_combine<<<NH/256, 256, 0, stream>>>(XI, Y, XI);   // XI now holds XM planes

  float* XO = Y;  // Y consumed; reuse as output-mix buffer
  k_gemm<64,64,64,4,64><<<dim3((NN   +127)/128,1),256,0,stream>>>(XI,                 WIo, nullptr, XO,                 NN,   2, nullptr);
  k_gemm<64,64,64,4,64><<<dim3((3*NN +127)/128,1),256,0,stream>>>(XI + (size_t)NH,    WAo, nullptr, XO + (size_t)NH,    3*NN, 2, nullptr);
  k_gemm<64,64,64,4,64><<<dim3((6*NN +127)/128,1),256,0,stream>>>(XI + (size_t)4*NH,  WSo, nullptr, XO + (size_t)4*NH,  6*NN, 2, nullptr);

  k_final<<<NH/256, 256, 0, stream>>>(XD, XO, q, out);
}

// Round 5
// 1430.405 us; speedup vs baseline: 1.5357x; 1.0293x over previous
//
#include <hip/hip_runtime.h>

#define NN 25000
#define HH 64
#define EE 400000
#define NH (NN*HH)

typedef __attribute__((ext_vector_type(8))) short bf16x8;
typedef __attribute__((ext_vector_type(4))) float f32x4;

__device__ __forceinline__ float silu_f(float x){
  return __fdividef(x, 1.0f + __expf(-x));
}
__device__ __forceinline__ short f2bf(float x){
  unsigned u = __float_as_uint(x);
  unsigned r = (u + 0x7FFFu + ((u>>16)&1u)) >> 16;
  return (short)r;
}
__device__ __forceinline__ float bf2f(short h){
  return __uint_as_float(((unsigned)(unsigned short)h)<<16);
}
// 4-term split product: (ah+al)(bh+bl) — error ~2^-18 relative
__device__ __forceinline__ f32x4 mfma4(bf16x8 ah, bf16x8 al, bf16x8 bh, bf16x8 bl, f32x4 acc){
  acc = __builtin_amdgcn_mfma_f32_16x16x32_bf16(ah, bh, acc, 0, 0, 0);
  acc = __builtin_amdgcn_mfma_f32_16x16x32_bf16(ah, bl, acc, 0, 0, 0);
  acc = __builtin_amdgcn_mfma_f32_16x16x32_bf16(al, bh, acc, 0, 0, 0);
  acc = __builtin_amdgcn_mfma_f32_16x16x32_bf16(al, bl, acc, 0, 0, 0);
  return acc;
}

__device__ __forceinline__ void mm3(float* __restrict__ C, const float* __restrict__ A,
                                    const float* __restrict__ B){
  #pragma unroll
  for (int i=0;i<3;i++)
    #pragma unroll
    for (int j=0;j<3;j++)
      C[i*3+j] = A[i*3+0]*B[0*3+j] + A[i*3+1]*B[1*3+j] + A[i*3+2]*B[2*3+j];
}
__device__ __forceinline__ void build3(float* __restrict__ M, const float* __restrict__ c){
  M[0] =  c[0]+c[4]; M[1] =  c[1]+c[5]; M[2] =  c[2]+c[6];
  M[3] = -c[1]+c[5]; M[4] =  c[0]+c[7]; M[5] =  c[3]+c[8];
  M[6] = -c[2]+c[6]; M[7] = -c[3]+c[8]; M[8] =  c[0]+c[9];
}
__device__ __forceinline__ void decomp3(const float* __restrict__ M, float* __restrict__ c){
  float I = (M[0]+M[4]+M[8]) * (1.0f/3.0f);
  c[0]=I;
  c[1]=0.5f*(M[1]-M[3]); c[2]=0.5f*(M[2]-M[6]); c[3]=0.5f*(M[5]-M[7]);
  c[4]=M[0]-I; c[5]=0.5f*(M[1]+M[3]); c[6]=0.5f*(M[2]+M[6]);
  c[7]=M[4]-I; c[8]=0.5f*(M[5]+M[7]); c[9]=M[8]-I;
}

__global__ __launch_bounds__(256) void k_prep(const float* __restrict__ X, float* __restrict__ XD){
  int idx = blockIdx.x*256 + threadIdx.x;
  if (idx >= NH) return;
  const float* t = X + (size_t)idx*9;
  float m[9];
  float n2 = 0.f;
  #pragma unroll
  for (int i=0;i<9;i++){ m[i] = t[i]; n2 += m[i]*m[i]; }
  float inv = __fdividef(1.0f, n2 + 1.0f);
  #pragma unroll
  for (int i=0;i<9;i++) m[i] *= inv;
  float c[10]; decomp3(m, c);
  #pragma unroll
  for (int i=0;i<10;i++) XD[i*NH + idx] = c[i];
}

// pre-split MLP weights into bf16 hi/lo (runs every launch; deterministic)
__global__ __launch_bounds__(256) void k_prep_w(
    const float* __restrict__ W1, const float* __restrict__ W2, const float* __restrict__ W3,
    short* __restrict__ W1h, short* __restrict__ W1l,
    short* __restrict__ W2h, short* __restrict__ W2l,
    short* __restrict__ W3h, short* __restrict__ W3l){
  int i = blockIdx.x*256 + threadIdx.x;
  if (i < 2048){
    float v = W1[i]; short h = f2bf(v); W1h[i]=h; W1l[i]=f2bf(v - bf2f(h));
  } else if (i < 10240){
    int j = i - 2048;
    float v = W2[j]; short h = f2bf(v); W2h[j]=h; W2l[j]=f2bf(v - bf2f(h));
  } else if (i < 34816){
    int j = i - 10240;
    float v = W3[j]; short h = f2bf(v); W3h[j]=h; W3l[j]=f2bf(v - bf2f(h));
  }
}

// ---------------- fused edge pipeline: MLP(32->64->128->192) + scatter ----------------------
// block = 256 thr (4 waves), 64 edges. Activations in LDS (split-bf16); weights read
// directly from pre-split global arrays (L2-hot, no LDS staging, no per-tile barriers).
// LDS map (bytes):
//  H1 hi/lo: 0 / 9216            (64 rows x 72 shorts)   ends 18432
//  H2 hi/lo: 18432 / 35840       (64 rows x 136 shorts)  ends 53248
//  EA hi/lo: 18432 / 23552       (alias H2; EA dead before H2 written)
//  F fp32:   0 (64 x 196)        aliases H1+H2, written last
//  cut:      53248 (64 f32)
#define O_H1H 0
#define O_H1L 9216
#define O_H2H 18432
#define O_H2L 35840
#define O_EAH 18432
#define O_EAL 23552
#define O_F   0
#define O_CUT 53248
#define SMEM_BYTES 53504

__global__ __launch_bounds__(256) void k_edge_fused(
    const float* __restrict__ ea, const float* __restrict__ ew,
    const int* __restrict__ ei,
    const short* __restrict__ W1h, const short* __restrict__ W1l, const float* __restrict__ b1,
    const short* __restrict__ W2h, const short* __restrict__ W2l, const float* __restrict__ b2,
    const short* __restrict__ W3h, const short* __restrict__ W3l, const float* __restrict__ b3,
    const float* __restrict__ XD, float* __restrict__ Y)
{
  __shared__ char smem[SMEM_BYTES] __attribute__((aligned(16)));
  const int tid  = threadIdx.x;
  const int w    = tid >> 6;
  const int l    = tid & 63;
  const int quad = l >> 4;
  const int nin  = l & 15;
  const int e0   = blockIdx.x * 64;

  // ---- P0: stage edge_attr (hi/lo split) + cutoffs ----
  #pragma unroll
  for (int g=0; g<2; g++){                       // 512 float4 over EA [64][32]
    int gi = tid + g*256;
    int row = gi >> 3, c4 = gi & 7;
    float4 v = *(const float4*)&ea[(size_t)(e0+row)*32 + c4*4];
    int be = row*40 + c4*4;
    short h;
    h = f2bf(v.x); ((short*)(smem+O_EAH))[be+0]=h; ((short*)(smem+O_EAL))[be+0]=f2bf(v.x-bf2f(h));
    h = f2bf(v.y); ((short*)(smem+O_EAH))[be+1]=h; ((short*)(smem+O_EAL))[be+1]=f2bf(v.y-bf2f(h));
    h = f2bf(v.z); ((short*)(smem+O_EAH))[be+2]=h; ((short*)(smem+O_EAL))[be+2]=f2bf(v.z-bf2f(h));
    h = f2bf(v.w); ((short*)(smem+O_EAH))[be+3]=h; ((short*)(smem+O_EAL))[be+3]=f2bf(v.w-bf2f(h));
  }
  if (tid < 64){
    float wv = ew[e0+tid];
    float c = 0.5f*(__cosf(wv*0.6283185307179586f)+1.0f);
    ((float*)(smem+O_CUT))[tid] = (wv < 5.0f) ? c : 0.0f;
  }
  __syncthreads();

  // ---- P1: H1 = silu(EA @ W1^T + b1), M=64 N=64 K=32; B-frags from global ----
  {
    bf16x8 ah = *(const bf16x8*)(smem + O_EAH + (w*16+nin)*80 + quad*16);
    bf16x8 al = *(const bf16x8*)(smem + O_EAL + (w*16+nin)*80 + quad*16);
    f32x4 acc[4];
    #pragma unroll
    for (int nt=0; nt<4; nt++){
      f32x4 z = {0.f,0.f,0.f,0.f};
      bf16x8 bh = *(const bf16x8*)&W1h[(nt*16+nin)*32 + quad*8];
      bf16x8 bl = *(const bf16x8*)&W1l[(nt*16+nin)*32 + quad*8];
      acc[nt] = mfma4(ah, al, bh, bl, z);
    }
    #pragma unroll
    for (int nt=0; nt<4; nt++){
      float bb = b1[nt*16+nin];
      #pragma unroll
      for (int r=0; r<4; r++){
        float v = silu_f(acc[nt][r] + bb);
        int row = w*16 + quad*4 + r, col = nt*16 + nin;
        short hi = f2bf(v); short lo = f2bf(v - bf2f(hi));
        ((short*)(smem+O_H1H))[row*72 + col] = hi;
        ((short*)(smem+O_H1L))[row*72 + col] = lo;
      }
    }
  }
  __syncthreads();

  // ---- P2: H2 = silu(H1 @ W2^T + b2), M=64 N=128 K=64 ----
  {
    f32x4 acc[8];
    #pragma unroll
    for (int i=0;i<8;i++){ f32x4 z = {0.f,0.f,0.f,0.f}; acc[i]=z; }
    #pragma unroll
    for (int kt=0; kt<2; kt++){
      bf16x8 ah = *(const bf16x8*)(smem + O_H1H + (w*16+nin)*144 + kt*64 + quad*16);
      bf16x8 al = *(const bf16x8*)(smem + O_H1L + (w*16+nin)*144 + kt*64 + quad*16);
      #pragma unroll
      for (int nt=0; nt<8; nt++){
        bf16x8 bh = *(const bf16x8*)&W2h[(nt*16+nin)*64 + kt*32 + quad*8];
        bf16x8 bl = *(const bf16x8*)&W2l[(nt*16+nin)*64 + kt*32 + quad*8];
        acc[nt] = mfma4(ah, al, bh, bl, acc[nt]);
      }
    }
    // H2 region aliases EA; EA dead since P1 (sync above guarantees visibility ordering)
    #pragma unroll
    for (int nt=0; nt<8; nt++){
      float bb = b2[nt*16+nin];
      #pragma unroll
      for (int r=0; r<4; r++){
        float v = silu_f(acc[nt][r] + bb);
        int row = w*16 + quad*4 + r, col = nt*16 + nin;
        short hi = f2bf(v); short lo = f2bf(v - bf2f(hi));
        ((short*)(smem+O_H2H))[row*136 + col] = hi;
        ((short*)(smem+O_H2L))[row*136 + col] = lo;
      }
    }
  }
  __syncthreads();

  // ---- P3: F = silu(H2 @ W3^T + b3) * cutoff, M=64 N=192 K=128 ----
  f32x4 acc3[12];
  #pragma unroll
  for (int i=0;i<12;i++){ f32x4 z = {0.f,0.f,0.f,0.f}; acc3[i]=z; }
  #pragma unroll
  for (int kt=0; kt<4; kt++){
    bf16x8 ah = *(const bf16x8*)(smem + O_H2H + (w*16+nin)*272 + kt*64 + quad*16);
    bf16x8 al = *(const bf16x8*)(smem + O_H2L + (w*16+nin)*272 + kt*64 + quad*16);
    #pragma unroll
    for (int nt=0; nt<12; nt++){
      bf16x8 bh = *(const bf16x8*)&W3h[(nt*16+nin)*128 + kt*32 + quad*8];
      bf16x8 bl = *(const bf16x8*)&W3l[(nt*16+nin)*128 + kt*32 + quad*8];
      acc3[nt] = mfma4(ah, al, bh, bl, acc3[nt]);
    }
  }
  __syncthreads();                // all H2 reads done; F aliases H1+H2
  #pragma unroll
  for (int nt=0; nt<12; nt++){
    float bb = b3[nt*16+nin];
    #pragma unroll
    for (int r=0; r<4; r++){
      int row = w*16 + quad*4 + r, col = nt*16 + nin;
      float v = silu_f(acc3[nt][r] + bb) * ((float*)(smem+O_CUT))[row];
      ((float*)(smem+O_F))[row*196 + col] = v;
    }
  }
  __syncthreads();

  // ---- P4: scatter — wave handles its own 16 edges, lane = channel h; 9 comps (S22 = -(S00+S11)) ----
  for (int t=0; t<16; t++){
    int el = w*16 + t;
    int e  = e0 + el;
    int dst = ei[e]*64 + l;
    int src = ei[EE+e]*64 + l;
    const float* fb = (const float*)(smem + O_F + el*784 + l*12);
    float f0 = fb[0], f1 = fb[1], f2 = fb[2];
    atomicAdd(&Y[0*NH+dst], f0*XD[0*NH+src]);
    atomicAdd(&Y[1*NH+dst], f1*XD[1*NH+src]);
    atomicAdd(&Y[2*NH+dst], f1*XD[2*NH+src]);
    atomicAdd(&Y[3*NH+dst], f1*XD[3*NH+src]);
    atomicAdd(&Y[4*NH+dst], f2*XD[4*NH+src]);
    atomicAdd(&Y[5*NH+dst], f2*XD[5*NH+src]);
    atomicAdd(&Y[6*NH+dst], f2*XD[6*NH+src]);
    atomicAdd(&Y[7*NH+dst], f2*XD[7*NH+src]);
    atomicAdd(&Y[8*NH+dst], f2*XD[8*NH+src]);
  }
}

// ---------------- node-side fp32 GEMM (plane channel mixing) -------------
template<int K, int KS, int NT, int TO, int NOUT>
__global__ __launch_bounds__(256) void k_gemm(const float* __restrict__ In,
                       const float* __restrict__ W,
                       float* __restrict__ Out, int M){
  constexpr int KSP = KS + 4;
  constexpr int F4R = KS/4;
  __shared__ __align__(16) float sA[128*KSP];
  __shared__ __align__(16) float sW[NT*KSP];
  const int tid = threadIdx.x;
  const int te = tid >> 4;
  const int to = tid & 15;
  const int e0 = blockIdx.x * 128;
  const int ob = blockIdx.y * NT;
  float acc[8][TO];
  #pragma unroll
  for (int s=0;s<8;s++)
    #pragma unroll
    for (int r=0;r<TO;r++) acc[s][r]=0.f;

  for (int kb = 0; kb < K; kb += KS){
    if (kb) __syncthreads();
    #pragma unroll
    for (int g = 0; g < 128*F4R/256; g++){
      int gi = tid + g*256;
      int row = gi / F4R, c4 = gi % F4R;
      float4 v = make_float4(0.f,0.f,0.f,0.f);
      if (e0 + row < M) v = *(const float4*)&In[(size_t)(e0+row)*K + kb + c4*4];
      int c4p = c4 ^ ((row>>3)&3);
      *(float4*)&sA[row*KSP + c4p*4] = v;
    }
    #pragma unroll
    for (int g = 0; g < NT*F4R/256; g++){
      int gi = tid + g*256;
      int row = gi / F4R, c4 = gi % F4R;
      float4 v = *(const float4*)&W[(size_t)(ob+row)*K + kb + c4*4];
      int c4p = c4 ^ ((row>>3)&3);
      *(float4*)&sW[row*KSP + c4p*4] = v;
    }
    __syncthreads();
    #pragma unroll 4
    for (int k4 = 0; k4 < F4R; k4++){
      float4 aa[8], ww[TO];
      #pragma unroll
      for (int s=0;s<8;s++){
        int row = te*8+s;
        aa[s] = *(const float4*)&sA[row*KSP + (k4 ^ ((row>>3)&3))*4];
      }
      #pragma unroll
      for (int r=0;r<TO;r++){
        int row = to*TO+r;
        ww[r] = *(const float4*)&sW[row*KSP + (k4 ^ ((row>>3)&3))*4];
      }
      #pragma unroll
      for (int s=0;s<8;s++)
        #pragma unroll
        for (int r=0;r<TO;r++){
          acc[s][r] += aa[s].x*ww[r].x;
          acc[s][r] += aa[s].y*ww[r].y;
          acc[s][r] += aa[s].z*ww[r].z;
          acc[s][r] += aa[s].w*ww[r].w;
        }
    }
  }
  #pragma unroll
  for (int s=0;s<8;s++){
    int eg = e0 + te*8 + s;
    if (eg >= M) continue;
    #pragma unroll
    for (int r=0;r<TO;r++){
      int o = ob + to*TO + r;
      Out[(size_t)eg*NOUT + o] = acc[s][r];
    }
  }
}

__global__ __launch_bounds__(256) void k_combine(const float* __restrict__ XI, const float* __restrict__ Y,
                          float* __restrict__ XM){
  int idx = blockIdx.x*256 + threadIdx.x;
  if (idx >= NH) return;
  float xi[10], yc[10];
  #pragma unroll
  for (int c=0;c<10;c++) xi[c]=XI[c*NH+idx];
  #pragma unroll
  for (int c=0;c<9;c++)  yc[c]=Y[c*NH+idx];
  yc[9] = -(yc[4]+yc[7]);        // S traceless: S22 = -(S00+S11)
  float Xin[9], Ym[9], Am[9], Bm[9];
  build3(Xin, xi); build3(Ym, yc);
  mm3(Am, Ym, Xin);
  mm3(Bm, Xin, Ym);
  float Xn[9]; float n2 = 0.f;
  #pragma unroll
  for (int i=0;i<9;i++){ Xn[i] = Am[i]+Bm[i]; n2 += Xn[i]*Xn[i]; }
  float inv = __fdividef(1.0f, n2 + 1.0f);
  #pragma unroll
  for (int i=0;i<9;i++) Xn[i] *= inv;
  float c[10]; decomp3(Xn, c);
  #pragma unroll
  for (int i=0;i<10;i++) XM[i*NH+idx] = c[i];
}

__global__ __launch_bounds__(256) void k_final(const float* __restrict__ XD, const float* __restrict__ XO,
                        const float* __restrict__ q, float* __restrict__ out){
  int idx = blockIdx.x*256 + threadIdx.x;
  if (idx >= NH) return;
  float xd[10], xo[10];
  #pragma unroll
  for (int c=0;c<10;c++){ xd[c]=XD[c*NH+idx]; xo[c]=XO[c*NH+idx]; }
  float Xn[9], dX[9], D2[9];
  build3(Xn, xd); build3(dX, xo);
  mm3(D2, dX, dX);
  float cf = 1.0f + 0.1f*q[idx>>6];
  float* o = out + (size_t)idx*9;
  #pragma unroll
  for (int i=0;i<9;i++) o[i] = Xn[i] + (dX[i]+D2[i])*cf;
}

extern "C" void kernel_launch(void* const* d_in, const int* in_sizes, int n_in,
                              void* d_out, int out_size, void* d_ws, size_t ws_size,
                              hipStream_t stream) {
  const float* X   = (const float*)d_in[0];
  const int*   ei  = (const int*)  d_in[1];
  const float* ew  = (const float*)d_in[2];
  const float* ea  = (const float*)d_in[3];
  const float* q   = (const float*)d_in[4];
  const float* W1  = (const float*)d_in[5];
  const float* b1  = (const float*)d_in[6];
  const float* W2  = (const float*)d_in[7];
  const float* b2  = (const float*)d_in[8];
  const float* W3  = (const float*)d_in[9];
  const float* b3  = (const float*)d_in[10];
  const float* WIi = (const float*)d_in[11];
  const float* WAi = (const float*)d_in[12];
  const float* WSi = (const float*)d_in[13];
  const float* WIo = (const float*)d_in[14];
  const float* WAo = (const float*)d_in[15];
  const float* WSo = (const float*)d_in[16];
  float* out = (float*)d_out;

  float* ws = (float*)d_ws;
  float* XD = ws;                        // 10*NH floats
  float* Y  = XD + (size_t)10*NH;        // 10*NH (9 planes used by agg; reused as XO)
  float* XI = Y  + (size_t)10*NH;        // 10*NH (later holds XM)
  short* WS = (short*)(XI + (size_t)10*NH);  // pre-split weights: 69632 shorts
  short* W1h = WS,         *W1l = WS + 2048;
  short* W2h = WS + 4096,  *W2l = WS + 12288;
  short* W3h = WS + 20480, *W3l = WS + 45056;

  hipMemsetAsync(Y, 0, (size_t)9*NH*sizeof(float), stream);
  k_prep_w<<<136, 256, 0, stream>>>(W1, W2, W3, W1h, W1l, W2h, W2l, W3h, W3l);
  k_prep<<<NH/256, 256, 0, stream>>>(X, XD);

  // fused edge pipeline: MLP + cutoff + gather/scatter, zero global edge scratch
  k_edge_fused<<<EE/64, 256, 0, stream>>>(ea, ew, ei, W1h, W1l, b1, W2h, W2l, b2,
                                          W3h, W3l, b3, XD, Y);

  // Xin = tensor_linear(Xn): three plane GEMMs (I / A / S share their W)
  k_gemm<64,64,64,4,64><<<dim3((NN   +127)/128,1),256,0,stream>>>(XD,                 WIi, XI,                 NN  );
  k_gemm<64,64,64,4,64><<<dim3((3*NN +127)/128,1),256,0,stream>>>(XD + (size_t)NH,    WAi, XI + (size_t)NH,    3*NN);
  k_gemm<64,64,64,4,64><<<dim3((6*NN +127)/128,1),256,0,stream>>>(XD + (size_t)4*NH,  WSi, XI + (size_t)4*NH,  6*NN);

  k_combine<<<NH/256, 256, 0, stream>>>(XI, Y, XI);   // XI now holds XM planes

  float* XO = Y;  // Y consumed; reuse as output-mix buffer
  k_gemm<64,64,64,4,64><<<dim3((NN   +127)/128,1),256,0,stream>>>(XI,                 WIo, XO,                 NN  );
  k_gemm<64,64,64,4,64><<<dim3((3*NN +127)/128,1),256,0,stream>>>(XI + (size_t)NH,    WAo, XO + (size_t)NH,    3*NN);
  k_gemm<64,64,64,4,64><<<dim3((6*NN +127)/128,1),256,0,stream>>>(XI + (size_t)4*NH,  WSo, XO + (size_t)4*NH,  6*NN);

  k_final<<<NH/256, 256, 0, stream>>>(XD, XO, q, out);
}